// Round 7
// baseline (309.595 us; speedup 1.0000x reference)
//
#include <hip/hip_runtime.h>

// Problem constants
#define E_TOT 8192
#define NB    32
#define H     128
#define EPG   256          // edges per graph (contiguous slots)

// Stage-1 T-GEMM: K = 33*64 (msg+bias) + 64 (root) = 2176
#define KH1   2176
#define TROW1 (2 * KH1)    // [Th | Tl] = 4352 shorts/row
// Stage-2/3 T-GEMM: K = 33*128 + 128 = 4352
#define KH2   4352
#define TROW2 (2 * KH2)    // 8704 shorts/row

typedef __attribute__((ext_vector_type(8))) short bf16x8;
typedef __attribute__((ext_vector_type(4))) float f32x4;

__device__ __forceinline__ unsigned short bf16_rne(float f) {
    unsigned int u = __float_as_uint(f);
    unsigned int r = (u + 0x7FFFu + ((u >> 16) & 1u)) >> 16;
    return (unsigned short)r;
}
__device__ __forceinline__ float bf16_to_f32(unsigned short h) {
    return __uint_as_float(((unsigned int)h) << 16);
}

__device__ __forceinline__ void gload_lds16(const void* g, void* l) {
    __builtin_amdgcn_global_load_lds(
        (const __attribute__((address_space(1))) unsigned int*)g,
        (__attribute__((address_space(3))) unsigned int*)l, 16, 0, 0);
}

// ---------------------------------------------------------------------------
// prep_all: all input-side preprocessing in ONE dispatch.
//   [0,34)    : Bt1n unit  (stage-1 weights -> [Wh(2176)|Wl(2176)])
//   [34,170)  : Bt2n units (stage-2 weights -> [Wh(4352)|Wl(4352)], 34x4)
//   [170,306) : Bt3n units (stage-3, same)
//   [306,562) : t1 units   (bucketed T1 aggregation, verbatim R4/R5)
// Block 0 zeroes the stats buffer.
// ---------------------------------------------------------------------------
union PrepSMem {
    struct { unsigned short HI[128][72]; unsigned short LO[128][72]; } b1;  // 36,864 B
    struct { unsigned short HI[128][40]; unsigned short LO[128][40]; } bt;  // 20,480 B
    struct { float xL[128][64]; float eaL[256][32]; short srcL[256];
             short lists[16][256]; int cnt[16]; } t1;                        // 74,304 B
};

__global__ __launch_bounds__(256)
void prep_all(const float* __restrict__ x, const float* __restrict__ ea,
              const int* __restrict__ esrc, const int* __restrict__ edst,
              const float* __restrict__ nn1w, const float* __restrict__ nn1b,
              const float* __restrict__ root1,
              const float* __restrict__ nn2w, const float* __restrict__ nn2b,
              const float* __restrict__ root2,
              const float* __restrict__ nn3w, const float* __restrict__ nn3b,
              const float* __restrict__ root3,
              unsigned short* __restrict__ Bt1, unsigned short* __restrict__ Bt2,
              unsigned short* __restrict__ Bt3, unsigned short* __restrict__ T1,
              float* __restrict__ stats)
{
    __shared__ PrepSMem sm;
    const int b   = blockIdx.x;
    const int tid = threadIdx.x;

    if (b < 34) {
        // ---- Bt1n unit (d = b), CIN=64: one slot per block ----
        if (b == 0)
            for (int i = tid; i < 768; i += 256) stats[i] = 0.f;
        const int d = b;
        const float* __restrict__ W =
            (d < 32) ? (nn1w + (size_t)d * 8192) : ((d == 32) ? nn1b : root1);
        for (int idx = tid; idx < 64 * 128; idx += 256) {
            const int ii = idx >> 7, o = idx & 127;
            const float v = W[ii * 128 + o];
            const unsigned short h = bf16_rne(v);
            sm.b1.HI[o][ii] = h;
            sm.b1.LO[o][ii] = bf16_rne(v - bf16_to_f32(h));
        }
        __syncthreads();
        const int o = tid & 127, half = tid >> 7;
        const uint4* s4 = (const uint4*)(half ? &sm.b1.LO[o][0] : &sm.b1.HI[o][0]);
        uint4* d4 = (uint4*)(Bt1 + (size_t)o * TROW1 + (half ? KH1 : 0) + d * 64);
        #pragma unroll
        for (int q = 0; q < 8; ++q) d4[q] = s4[q];
    } else if (b < 306) {
        // ---- Bt2n/Bt3n unit: slot d (0..33), i-chunk of 32, CIN=128 ----
        const int unit  = b - 34;
        const int stage = unit / 136;            // 0: stage2, 1: stage3
        const int u2    = unit - stage * 136;
        const int d  = u2 >> 2;
        const int i0 = (u2 & 3) * 32;
        const float* __restrict__ W = (stage == 0)
            ? ((d < 32) ? (nn2w + (size_t)d * 16384) : ((d == 32) ? nn2b : root2))
            : ((d < 32) ? (nn3w + (size_t)d * 16384) : ((d == 32) ? nn3b : root3));
        unsigned short* __restrict__ Bt = (stage == 0) ? Bt2 : Bt3;

        for (int idx = tid; idx < 32 * 128; idx += 256) {
            const int ii = idx >> 7, o = idx & 127;
            const float v = W[(size_t)(i0 + ii) * 128 + o];
            const unsigned short h = bf16_rne(v);
            sm.bt.HI[o][ii] = h;
            sm.bt.LO[o][ii] = bf16_rne(v - bf16_to_f32(h));
        }
        __syncthreads();
        const int o = tid & 127, half = tid >> 7;
        const uint4* s4 = (const uint4*)(half ? &sm.bt.LO[o][0] : &sm.bt.HI[o][0]);
        uint4* d4 = (uint4*)(Bt + (size_t)o * TROW2 + (half ? KH2 : 0) + d * 128 + i0);
        #pragma unroll
        for (int q = 0; q < 4; ++q) d4[q] = s4[q];   // 32 shorts
    } else {
        // ---- t1 unit (verbatim bucketed aggregation) ----
        const int u    = b - 306;
        const int g    = u >> 3;
        const int base = (u & 7) * 16;
        const int wv   = tid >> 6;
        const int ln   = tid & 63;

        if (tid < 16) sm.t1.cnt[tid] = 0;
        for (int idx = tid; idx < 128 * 64; idx += 256)
            sm.t1.xL[idx >> 6][idx & 63] = x[(size_t)g * 8192 + idx];
        for (int idx = tid; idx < 256 * 32; idx += 256)
            sm.t1.eaL[idx >> 5][idx & 31] = ea[(size_t)g * 8192 + idx];
        __syncthreads();

        {
            const int e = tid;
            sm.t1.srcL[e] = (short)(esrc[g * EPG + e] - g * 128);
            const int r = (edst[g * EPG + e] - g * 128) - base;
            if (r >= 0 && r < 16) {
                const int pos = atomicAdd(&sm.t1.cnt[r], 1);
                sm.t1.lists[r][pos] = (short)e;
            }
        }
        __syncthreads();

        #pragma unroll
        for (int j = 0; j < 4; ++j) {
            const int r = wv * 4 + j;
            const int uu = base + r;
            float acc[33];
            #pragma unroll
            for (int d = 0; d < 33; ++d) acc[d] = 0.f;

            const int n = sm.t1.cnt[r];
            for (int t = 0; t < n; ++t) {
                const int e = sm.t1.lists[r][t];
                const float xv = sm.t1.xL[sm.t1.srcL[e]][ln];
                #pragma unroll
                for (int d = 0; d < 32; ++d) acc[d] += sm.t1.eaL[e][d] * xv;
                acc[32] += xv;
            }

            unsigned short* row = T1 + (size_t)(g * 128 + uu) * TROW1;
            #pragma unroll
            for (int d = 0; d < 33; ++d) {
                const unsigned short hb = bf16_rne(acc[d]);
                row[d * 64 + ln] = hb;
                row[KH1 + d * 64 + ln] = bf16_rne(acc[d] - bf16_to_f32(hb));
            }
            const float xv = sm.t1.xL[uu][ln];
            const unsigned short hb = bf16_rne(xv);
            row[2112 + ln] = hb;
            row[KH1 + 2112 + ln] = bf16_rne(xv - bf16_to_f32(hb));
        }
    }
}

// ---------------------------------------------------------------------------
// t_build<KROWS>: stage-2/3 T aggregation (CIN=128). Grid (NB, KROWS/8);
// block = (graph, chunk of 8 dst rows). Bucketed, exact f32, hi/lo split.
// T[u,k']: k' = [msg(33*128) | root(128)], sections [Th | Tl].
// ---------------------------------------------------------------------------
template<int KROWS>
__global__ __launch_bounds__(256)
void t_build(const float* __restrict__ x2,     // [NB*KROWS][128] f32 (pooled)
             const float* __restrict__ ea,
             const int* __restrict__ esrc, const int* __restrict__ edst,
             unsigned short* __restrict__ T)
{
    const int g    = blockIdx.x;
    const int base = blockIdx.y * 8;
    const int tid  = threadIdx.x;
    const int wv   = tid >> 6;
    const int ln   = tid & 63;

    __shared__ float xL[KROWS][128];
    __shared__ float eaL[256][32];
    __shared__ short srcL[256];
    __shared__ short lists[8][256];
    __shared__ int   cnt[8];

    if (tid < 8) cnt[tid] = 0;
    for (int idx = tid; idx < KROWS * 32; idx += 256)          // float4 loads
        ((float4*)&xL[0][0])[idx] = ((const float4*)(x2 + (size_t)g * KROWS * H))[idx];
    for (int idx = tid; idx < 256 * 8; idx += 256)
        ((float4*)&eaL[0][0])[idx] = ((const float4*)(ea + (size_t)g * 8192))[idx];
    __syncthreads();

    {
        const int e = tid;
        srcL[e] = (short)(esrc[g * EPG + e] - g * KROWS);      // garbage if invalid
        const int r = (edst[g * EPG + e] - g * KROWS) - base;  // invalid -> negative
        if (r >= 0 && r < 8) {
            const int pos = atomicAdd(&cnt[r], 1);
            lists[r][pos] = (short)e;
        }
    }
    __syncthreads();

    #pragma unroll
    for (int j = 0; j < 2; ++j) {
        const int r = wv * 2 + j;
        const int u = base + r;
        unsigned short* row = T + (size_t)(g * KROWS + u) * TROW2;
        const int n = cnt[r];

        #pragma unroll
        for (int half = 0; half < 2; ++half) {
            const int cc = ln + half * 64;
            float acc[33];
            #pragma unroll
            for (int d = 0; d < 33; ++d) acc[d] = 0.f;

            for (int t = 0; t < n; ++t) {
                const int e = lists[r][t];
                const float xv = xL[srcL[e]][cc];
                #pragma unroll
                for (int d = 0; d < 32; ++d) acc[d] += eaL[e][d] * xv;
                acc[32] += xv;
            }

            #pragma unroll
            for (int d = 0; d < 33; ++d) {
                const unsigned short hb = bf16_rne(acc[d]);
                row[d * 128 + cc] = hb;
                row[KH2 + d * 128 + cc] = bf16_rne(acc[d] - bf16_to_f32(hb));
            }
            const float xv = xL[u][cc];                        // root section
            const unsigned short hb = bf16_rne(xv);
            row[4224 + cc] = hb;
            row[KH2 + 4224 + cc] = bf16_rne(xv - bf16_to_f32(hb));
        }
    }
}

// ---------------------------------------------------------------------------
// hgemm_t<KHALF>: h-partials = T @ Btn^T, 3 split-bf16 sections
// (Th*Wh, Th*Wl, Tl*Wh), 17 k-steps per block, k-split = 3*(KHALF/32)/17.
// Grid (Mtiles, ksplit). Block c==0 adds bias.
// ---------------------------------------------------------------------------
template<int KHALF>
__global__ __launch_bounds__(256)
void hgemm_t(const unsigned short* __restrict__ A,    // [M][2*KHALF]
             const unsigned short* __restrict__ Bt,   // [128][2*KHALF]
             const float* __restrict__ bias,
             float* __restrict__ hpart)               // [ksplit][M][128]
{
    constexpr int TROW = 2 * KHALF;
    constexpr int SEC  = KHALF / 32;

    __shared__ unsigned short Alds[128 * 32];
    __shared__ unsigned short Blds[128 * 32];

    const int lane = threadIdx.x & 63;
    const int w    = threadIdx.x >> 6;
    const int wm = w >> 1, wn = w & 1;
    const int v0 = blockIdx.x * 128;
    const int c  = blockIdx.y;
    const int M  = gridDim.x * 128;

    f32x4 acc[4][4];
    #pragma unroll
    for (int i = 0; i < 4; ++i)
        #pragma unroll
        for (int j = 0; j < 4; ++j)
            acc[i][j] = (f32x4)(0.0f);

    const int arow = lane >> 2;
    const int acol = (lane & 3) * 8;
    const int koff = (lane >> 4) * 8;
    const int mrow = lane & 15;

    for (int t = c * 17; t < c * 17 + 17; ++t) {
        const int s  = t / SEC;                      // section 0,1,2
        const int ko = (t - s * SEC) * 32;
        const int aoff = (s == 2 ? KHALF : 0) + ko;  // s2 reads Tl
        const int boff = (s == 1 ? KHALF : 0) + ko;  // s1 reads Wl

        __syncthreads();
        #pragma unroll
        for (int tt = 0; tt < 2; ++tt) {
            const int cc = w * 2 + tt;
            const int r = cc * 16 + arow;
            gload_lds16(A  + (size_t)(v0 + r) * TROW + aoff + acol, &Alds[cc * 512]);
            gload_lds16(Bt + (size_t)r * TROW + boff + acol, &Blds[cc * 512]);
        }
        __syncthreads();

        bf16x8 a[4], b[4];
        #pragma unroll
        for (int f = 0; f < 4; ++f) {
            a[f] = *(const bf16x8*)&Alds[(wm * 64 + f * 16 + mrow) * 32 + koff];
            b[f] = *(const bf16x8*)&Blds[(wn * 64 + f * 16 + mrow) * 32 + koff];
        }
        #pragma unroll
        for (int fm = 0; fm < 4; ++fm)
            #pragma unroll
            for (int fn = 0; fn < 4; ++fn)
                acc[fm][fn] = __builtin_amdgcn_mfma_f32_16x16x32_bf16(
                    a[fm], b[fn], acc[fm][fn], 0, 0, 0);
    }

    float* out = hpart + (size_t)c * M * H;
    const int crow = (lane >> 4) * 4;
    const int ccol = lane & 15;
    #pragma unroll
    for (int fm = 0; fm < 4; ++fm) {
        const int gr = v0 + wm * 64 + fm * 16 + crow;
        #pragma unroll
        for (int fn = 0; fn < 4; ++fn) {
            const int col = wn * 64 + fn * 16 + ccol;
            const float bv = (c == 0) ? bias[col] : 0.f;
            #pragma unroll
            for (int r = 0; r < 4; ++r)
                out[(size_t)(gr + r) * H + col] = acc[fm][fn][r] + bv;
        }
    }
}

// ---------------------------------------------------------------------------
// bn_reduce<NSPLIT>: h = sum of partials; BN stats in the same pass.
// ---------------------------------------------------------------------------
template<int NSPLIT>
__global__ __launch_bounds__(256)
void bn_reduce(const float* __restrict__ hpart, float* __restrict__ h,
               float* __restrict__ gsum, float* __restrict__ gsumsq, int n)
{
    const int tid   = threadIdx.x;
    const int col   = tid & 127;
    const int rhalf = tid >> 7;
    float s = 0.f, sq = 0.f;
    for (int r = blockIdx.x * 2 + rhalf; r < n; r += gridDim.x * 2) {
        float v = 0.f;
        #pragma unroll
        for (int c = 0; c < NSPLIT; ++c)
            v += hpart[(size_t)c * n * H + (size_t)r * H + col];
        h[(size_t)r * H + col] = v;
        s += v; sq += v * v;
    }
    __shared__ float sh[256];
    sh[tid] = s;  __syncthreads();
    if (rhalf == 0) s += sh[tid + 128];
    __syncthreads();
    sh[tid] = sq; __syncthreads();
    if (rhalf == 0) {
        sq += sh[tid + 128];
        atomicAdd(&gsum[col], s);
        atomicAdd(&gsumsq[col], sq);
    }
}

// ---------------------------------------------------------------------------
// fused_pool: BN + ReLU + score + top-k + pooled-feature (x2) emission +
// edge remap. x2[g*k+nr] = y*score (f32) feeds t_build.
// ---------------------------------------------------------------------------
__global__ __launch_bounds__(256)
void fused_pool(const float* __restrict__ h,
                const float* __restrict__ gsum, const float* __restrict__ gsumsq,
                float n_f,
                const float* __restrict__ gamma, const float* __restrict__ beta,
                const float* __restrict__ pw,
                int npg, int k,
                const int* __restrict__ esrc_in, const int* __restrict__ edst_in,
                int* __restrict__ esrc_out, int* __restrict__ edst_out,
                float* __restrict__ x2out)           // [NB*k][128] f32
{
    const int g   = blockIdx.x;
    const int tid = threadIdx.x;
    const int wv  = tid >> 6;
    const int ln  = tid & 63;

    __shared__ float muL[128], rsL[128], gmL[128], btL[128], pwL[128];
    __shared__ float scoreL[128], red[128];
    __shared__ int   mapL[128];
    __shared__ float sinv;

    if (tid < 128) {
        const float mu  = gsum[tid] / n_f;
        const float var = gsumsq[tid] / n_f - mu * mu;
        muL[tid] = mu;
        rsL[tid] = rsqrtf(var + 1e-5f);
        gmL[tid] = gamma[tid];
        btL[tid] = beta[tid];
        const float p = pw[tid];
        pwL[tid] = p;
        red[tid] = p * p;
    }
    __syncthreads();
    for (int off = 64; off > 0; off >>= 1) {
        if (tid < off) red[tid] += red[tid + off];
        __syncthreads();
    }
    if (tid == 0) sinv = rsqrtf(red[0]);
    __syncthreads();

    for (int r = wv; r < npg; r += 4) {
        const float* hr = h + (size_t)(g * npg + r) * H;
        float p = 0.f;
        #pragma unroll
        for (int half = 0; half < 2; ++half) {
            const int c = ln + half * 64;
            const float y = fmaxf(gmL[c] * (hr[c] - muL[c]) * rsL[c] + btL[c], 0.f);
            p += y * pwL[c];
        }
        #pragma unroll
        for (int off = 32; off > 0; off >>= 1)
            p += __shfl_down(p, off, 64);
        if (ln == 0) scoreL[r] = tanhf(p * sinv);
    }
    __syncthreads();

    if (tid < npg) {
        const float si = scoreL[tid];
        int cnt = 0;
        for (int j = 0; j < npg; ++j) {
            const float sj = scoreL[j];
            cnt += (sj > si) || (sj == si && j < tid);
        }
        mapL[tid] = (cnt < k) ? cnt : -1;
    }
    __syncthreads();

    for (int r = wv; r < npg; r += 4) {
        const int nr = mapL[r];
        if (nr < 0) continue;
        const float sc = scoreL[r];
        const float* hr = h + (size_t)(g * npg + r) * H;
        float* xrow = x2out + (size_t)(g * k + nr) * H;
        #pragma unroll
        for (int half = 0; half < 2; ++half) {
            const int c = ln + half * 64;
            const float y = fmaxf(gmL[c] * (hr[c] - muL[c]) * rsL[c] + btL[c], 0.f);
            xrow[c] = y * sc;
        }
    }

    {
        const int e = g * EPG + tid;
        const int s = esrc_in[e];
        int ns = -1, nd = -1;
        if (s >= 0) {
            const int ms = mapL[s - g * npg];
            const int md = mapL[edst_in[e] - g * npg];
            if (ms >= 0 && md >= 0) { ns = g * k + ms; nd = g * k + md; }
        }
        esrc_out[e] = ns; edst_out[e] = nd;
    }
}

// ---------------------------------------------------------------------------
// fused_pool_final: stage-3 pool (npg=32,k=16) + mean-pool + MLP + sigmoid.
// (unchanged baseline)
// ---------------------------------------------------------------------------
__global__ __launch_bounds__(256)
void fused_pool_final(const float* __restrict__ h,
                      const float* __restrict__ gsum, const float* __restrict__ gsumsq,
                      float n_f,
                      const float* __restrict__ gamma, const float* __restrict__ beta,
                      const float* __restrict__ pw,
                      const float* __restrict__ lin1_w, const float* __restrict__ lin1_b,
                      const float* __restrict__ lin2_w, const float* __restrict__ lin2_b,
                      float* __restrict__ out)
{
    const int g   = blockIdx.x;
    const int tid = threadIdx.x;
    const int wv  = tid >> 6;
    const int ln  = tid & 63;
    const int npg = 32, k = 16;

    __shared__ float muL[128], rsL[128], gmL[128], btL[128], pwL[128];
    __shared__ float scoreL[32], red[128], gmean[128], h1c[64];
    __shared__ int   mapL[32];
    __shared__ float sinv;

    if (tid < 128) {
        const float mu  = gsum[tid] / n_f;
        const float var = gsumsq[tid] / n_f - mu * mu;
        muL[tid] = mu;
        rsL[tid] = rsqrtf(var + 1e-5f);
        gmL[tid] = gamma[tid];
        btL[tid] = beta[tid];
        const float p = pw[tid];
        pwL[tid] = p;
        red[tid] = p * p;
    }
    __syncthreads();
    for (int off = 64; off > 0; off >>= 1) {
        if (tid < off) red[tid] += red[tid + off];
        __syncthreads();
    }
    if (tid == 0) sinv = rsqrtf(red[0]);
    __syncthreads();

    for (int r = wv; r < npg; r += 4) {
        const float* hr = h + (size_t)(g * npg + r) * H;
        float p = 0.f;
        #pragma unroll
        for (int half = 0; half < 2; ++half) {
            const int c = ln + half * 64;
            const float y = fmaxf(gmL[c] * (hr[c] - muL[c]) * rsL[c] + btL[c], 0.f);
            p += y * pwL[c];
        }
        #pragma unroll
        for (int off = 32; off > 0; off >>= 1)
            p += __shfl_down(p, off, 64);
        if (ln == 0) scoreL[r] = tanhf(p * sinv);
    }
    __syncthreads();

    if (tid < npg) {
        const float si = scoreL[tid];
        int cnt = 0;
        for (int j = 0; j < npg; ++j) {
            const float sj = scoreL[j];
            cnt += (sj > si) || (sj == si && j < tid);
        }
        mapL[tid] = (cnt < k) ? cnt : -1;
    }
    __syncthreads();

    if (tid < 128) {
        float acc = 0.f;
        for (int r = 0; r < npg; ++r) {
            if (mapL[r] < 0) continue;
            const float hv = h[(size_t)(g * npg + r) * H + tid];
            const float y  = fmaxf(gmL[tid] * (hv - muL[tid]) * rsL[tid] + btL[tid], 0.f);
            acc += y * scoreL[r];
        }
        gmean[tid] = acc * (1.0f / 16.0f);
    }
    __syncthreads();

    if (tid < 64) {
        float acc = lin1_b[tid];
        for (int o = 0; o < 128; ++o) acc += gmean[o] * lin1_w[o * 64 + tid];
        h1c[tid] = fmaxf(acc, 0.f);
    }
    __syncthreads();
    if (tid == 0) {
        float z = lin2_b[0];
        for (int j = 0; j < 64; ++j) z += h1c[j] * lin2_w[j];
        out[g] = 1.0f / (1.0f + expf(-z));
    }
}

extern "C" void kernel_launch(void* const* d_in, const int* in_sizes, int n_in,
                              void* d_out, int out_size, void* d_ws, size_t ws_size,
                              hipStream_t stream)
{
    const float* x        = (const float*)d_in[0];
    const int*   ei       = (const int*)  d_in[1];
    const float* eattr    = (const float*)d_in[2];
    const float* nn1_w    = (const float*)d_in[4];
    const float* nn1_b    = (const float*)d_in[5];
    const float* root1    = (const float*)d_in[6];
    const float* bias1    = (const float*)d_in[7];
    const float* nn2_w    = (const float*)d_in[8];
    const float* nn2_b    = (const float*)d_in[9];
    const float* root2    = (const float*)d_in[10];
    const float* bias2    = (const float*)d_in[11];
    const float* nn3_w    = (const float*)d_in[12];
    const float* nn3_b    = (const float*)d_in[13];
    const float* root3    = (const float*)d_in[14];
    const float* bias3    = (const float*)d_in[15];
    const float* gamma1   = (const float*)d_in[16];
    const float* beta1    = (const float*)d_in[17];
    const float* gamma2   = (const float*)d_in[18];
    const float* beta2    = (const float*)d_in[19];
    const float* gamma3   = (const float*)d_in[20];
    const float* beta3    = (const float*)d_in[21];
    const float* pw1      = (const float*)d_in[22];
    const float* pw2      = (const float*)d_in[23];
    const float* pw3      = (const float*)d_in[24];
    const float* lin1_w   = (const float*)d_in[25];
    const float* lin1_b   = (const float*)d_in[26];
    const float* lin2_w   = (const float*)d_in[27];
    const float* lin2_b   = (const float*)d_in[28];

    const int* ei_src = ei;
    const int* ei_dst = ei + E_TOT;

    char* wp = (char*)d_ws;
    auto alloc = [&](size_t bytes) { char* p = wp; wp += (bytes + 255) & ~(size_t)255; return p; };
    float* h1   = (float*)alloc(4096 * 128 * 4);
    float* h2   = (float*)alloc(2048 * 128 * 4);
    float* h3   = (float*)alloc(1024 * 128 * 4);
    int*   src1 = (int*)alloc(E_TOT * 4);
    int*   dst1 = (int*)alloc(E_TOT * 4);
    int*   src2 = (int*)alloc(E_TOT * 4);
    int*   dst2 = (int*)alloc(E_TOT * 4);
    float* stats = (float*)alloc(6 * 128 * 4);
    float* x2   = (float*)alloc((size_t)2048 * 128 * 4);   // pooled feats, stage2
    float* x3   = (float*)alloc((size_t)1024 * 128 * 4);   // pooled feats, stage3
    unsigned short* Bt1n = (unsigned short*)alloc((size_t)128 * TROW1 * 2);
    unsigned short* Bt2n = (unsigned short*)alloc((size_t)128 * TROW2 * 2);
    unsigned short* Bt3n = (unsigned short*)alloc((size_t)128 * TROW2 * 2);
    unsigned short* T1   = (unsigned short*)alloc((size_t)4096 * TROW1 * 2);  // 35.7 MB
    unsigned short* T2   = (unsigned short*)alloc((size_t)2048 * TROW2 * 2);  // 35.7 MB
    unsigned short* T3   = (unsigned short*)alloc((size_t)1024 * TROW2 * 2);  // 17.8 MB
    float* hpart = (float*)alloc((size_t)24 * 2048 * 128 * 4);                // 25.2 MB (reused)

    // ---- ALL preprocessing + stats zeroing: ONE dispatch ----
    prep_all<<<562, 256, 0, stream>>>(x, eattr, ei_src, ei_dst,
                                      nn1_w, nn1_b, root1,
                                      nn2_w, nn2_b, root2,
                                      nn3_w, nn3_b, root3,
                                      Bt1n, Bt2n, Bt3n, T1, stats);

    // ---- Stage 1 ----
    hgemm_t<KH1><<<dim3(32, 12), 256, 0, stream>>>(T1, Bt1n, bias1, hpart);
    bn_reduce<12><<<256, 256, 0, stream>>>(hpart, h1, stats, stats + 128, 4096);
    fused_pool<<<NB, 256, 0, stream>>>(h1, stats, stats + 128, 4096.0f,
                                       gamma1, beta1, pw1, 128, 64,
                                       ei_src, ei_dst, src1, dst1, x2);

    // ---- Stage 2 (aggregate-first, no Y) ----
    t_build<64><<<dim3(NB, 8), 256, 0, stream>>>(x2, eattr, src1, dst1, T2);
    hgemm_t<KH2><<<dim3(16, 24), 256, 0, stream>>>(T2, Bt2n, bias2, hpart);
    bn_reduce<24><<<256, 256, 0, stream>>>(hpart, h2, stats + 256, stats + 384, 2048);
    fused_pool<<<NB, 256, 0, stream>>>(h2, stats + 256, stats + 384, 2048.0f,
                                       gamma2, beta2, pw2, 64, 32,
                                       src1, dst1, src2, dst2, x3);

    // ---- Stage 3 (aggregate-first, no Y) ----
    t_build<32><<<dim3(NB, 4), 256, 0, stream>>>(x3, eattr, src2, dst2, T3);
    hgemm_t<KH2><<<dim3(8, 24), 256, 0, stream>>>(T3, Bt3n, bias3, hpart);
    bn_reduce<24><<<256, 256, 0, stream>>>(hpart, h3, stats + 512, stats + 640, 1024);
    fused_pool_final<<<NB, 256, 0, stream>>>(h3, stats + 512, stats + 640, 1024.0f,
                                             gamma3, beta3, pw3,
                                             lin1_w, lin1_b, lin2_w, lin2_b,
                                             (float*)d_out);
}